// Round 12
// baseline (323.509 us; speedup 1.0000x reference)
//
#include <hip/hip_runtime.h>
#include <hip/hip_bf16.h>
#include <math.h>

#define NHEADS 16
#define DHEAD  64
#define CHDIM  80
#define RQn    6
#define RKn    2
#define RVn    2
#define TT     2048
#define DDim   1024
#define NQK    800
#define GRID   512

using frag16 = __attribute__((ext_vector_type(8))) short;
using f32x4  = __attribute__((ext_vector_type(4))) float;
using f32x16 = __attribute__((ext_vector_type(16))) float;

#define AS1(p) ((const __attribute__((address_space(1))) unsigned int*)(p))
#define AS3(p) ((__attribute__((address_space(3))) unsigned int*)(p))

static __device__ __forceinline__ unsigned short bf16_bits(float f) {
    __hip_bfloat16 h = __float2bfloat16(f);
    return *(unsigned short*)&h;
}
static __device__ __forceinline__ unsigned int pk2(float a, float b) {
    return ((unsigned int)bf16_bits(b) << 16) | (unsigned int)bf16_bits(a);
}

// ---- device-scope grid barrier (hardened, r11 version) ----
static __device__ __forceinline__ void gbar(unsigned* cell) {
    __syncthreads();
    if (threadIdx.x == 0) {
        __builtin_amdgcn_s_waitcnt(0);
        __threadfence_system();
        __builtin_amdgcn_s_waitcnt(0);
        __hip_atomic_fetch_add(cell, 1u, __ATOMIC_SEQ_CST, __HIP_MEMORY_SCOPE_SYSTEM);
        while (__hip_atomic_load(cell, __ATOMIC_SEQ_CST, __HIP_MEMORY_SCOPE_SYSTEM) < (unsigned)GRID)
            __builtin_amdgcn_s_sleep(2);
        __threadfence_system();
        __builtin_amdgcn_s_waitcnt(0);
    }
    __syncthreads();
}

// ---- device GEMM (r9 64x128 structure), used only inside `front` phase 1 ----
static __device__ void dev_gemm(const __hip_bfloat16* __restrict__ A,
                                const __hip_bfloat16* __restrict__ W,
                                float* __restrict__ C,
                                int N, int K, int bm, int bn, char* smem)
{
    __hip_bfloat16* Asl = (__hip_bfloat16*)smem;            // [2][4096]
    __hip_bfloat16* Bsl = (__hip_bfloat16*)(smem + 16384);  // [2][8192]
    const int tid = threadIdx.x;
    const int w = tid >> 6, lane = tid & 63;
    const int l16 = lane & 15, quad = lane >> 4;

    int rSA[2], cSA[2];
    #pragma unroll
    for (int j = 0; j < 2; j++) {
        int L = (w * 2 + j) * 64 + lane;
        rSA[j] = L >> 3;
        cSA[j] = (L & 7) ^ (rSA[j] & 7);
    }
    int rSB[4], cSB[4];
    #pragma unroll
    for (int j = 0; j < 4; j++) {
        int L = (w * 4 + j) * 64 + lane;
        int r = L >> 3;
        cSB[j] = (L & 7) ^ (r & 7);
        int rb = bn + r;
        rSB[j] = (rb < N) ? rb : (N - 1);
    }

    f32x4 acc[4][2];
    #pragma unroll
    for (int mt = 0; mt < 4; mt++)
        #pragma unroll
        for (int nt = 0; nt < 2; nt++)
            acc[mt][nt] = (f32x4){0.f, 0.f, 0.f, 0.f};

    const int nK = K >> 6;
    #pragma unroll
    for (int j = 0; j < 2; j++)
        __builtin_amdgcn_global_load_lds(AS1(A + (size_t)(bm + rSA[j]) * K + cSA[j] * 8),
                                         AS3(&Asl[(w * 2 + j) * 512]), 16, 0, 0);
    #pragma unroll
    for (int j = 0; j < 4; j++)
        __builtin_amdgcn_global_load_lds(AS1(W + (size_t)rSB[j] * K + cSB[j] * 8),
                                         AS3(&Bsl[(w * 4 + j) * 512]), 16, 0, 0);

    for (int kk = 0; kk < nK; kk++) {
        const int cur = kk & 1;
        __syncthreads();
        if (kk + 1 < nK) {
            const int k1 = (kk + 1) * 64;
            #pragma unroll
            for (int j = 0; j < 2; j++)
                __builtin_amdgcn_global_load_lds(AS1(A + (size_t)(bm + rSA[j]) * K + k1 + cSA[j] * 8),
                                                 AS3(&Asl[(cur ^ 1) * 4096 + (w * 2 + j) * 512]), 16, 0, 0);
            #pragma unroll
            for (int j = 0; j < 4; j++)
                __builtin_amdgcn_global_load_lds(AS1(W + (size_t)rSB[j] * K + k1 + cSB[j] * 8),
                                                 AS3(&Bsl[(cur ^ 1) * 8192 + (w * 4 + j) * 512]), 16, 0, 0);
        }
        #pragma unroll
        for (int ks = 0; ks < 2; ks++) {
            frag16 af[4], bf[2];
            #pragma unroll
            for (int mt = 0; mt < 4; mt++) {
                int r = mt * 16 + l16;
                af[mt] = *(const frag16*)&Asl[cur * 4096 + r * 64 + (((ks * 4 + quad) ^ (r & 7)) * 8)];
            }
            #pragma unroll
            for (int nt = 0; nt < 2; nt++) {
                int r = w * 32 + nt * 16 + l16;
                bf[nt] = *(const frag16*)&Bsl[cur * 8192 + r * 64 + (((ks * 4 + quad) ^ (r & 7)) * 8)];
            }
            #pragma unroll
            for (int mt = 0; mt < 4; mt++)
                #pragma unroll
                for (int nt = 0; nt < 2; nt++)
                    acc[mt][nt] = __builtin_amdgcn_mfma_f32_16x16x32_bf16(af[mt], bf[nt], acc[mt][nt], 0, 0, 0);
        }
    }
    #pragma unroll
    for (int mt = 0; mt < 4; mt++) {
        #pragma unroll
        for (int reg = 0; reg < 4; reg++) {
            int row = bm + mt * 16 + quad * 4 + reg;
            #pragma unroll
            for (int nt = 0; nt < 2; nt++) {
                int col = bn + w * 32 + nt * 16 + l16;
                if (col < N) C[(size_t)row * N + col] = acc[mt][nt][reg];
            }
        }
    }
}

// ---- device qkv (r9 structure) ----
static __device__ void dev_qkv(const float* __restrict__ ab,
                               __hip_bfloat16* __restrict__ q, __hip_bfloat16* __restrict__ k,
                               __hip_bfloat16* __restrict__ vT, int vb, char* smem)
{
    float* sq  = (float*)smem;
    float* skv = (float*)(smem + 7680);
    __hip_bfloat16* vbuf = (__hip_bfloat16*)(smem + 12800);
    __syncthreads();
    const int tok0 = vb * 4;
    const int w = threadIdx.x >> 6;
    const int d = threadIdx.x & 63;
    const int token = tok0 + w;
    const int b = token / TT;
    const int t = token % TT;
    const float* aq  = ab + (size_t)token * NQK;
    const float* akv = aq + 480;
    for (int i = d; i < RQn * CHDIM; i += 64) sq[w * 480 + i] = aq[i];
    for (int i = d; i < (RKn + RVn) * CHDIM; i += 64) skv[w * 320 + i] = akv[i];
    const int i32 = d & 31;
    float inv_freq = powf(10000.0f, -(float)i32 / 32.0f);
    float fr = (float)t * inv_freq;
    float c = cosf(fr), s = sinf(fr);
    float rot[4];
    #pragma unroll
    for (int r = 0; r < 4; r++) {
        float x1 = skv[w * 320 + r * CHDIM + NHEADS + i32];
        float x2 = skv[w * 320 + r * CHDIM + NHEADS + 32 + i32];
        rot[r] = (d < 32) ? (x1 * c + x2 * s) : (-x1 * s + x2 * c);
    }
    float bqv[RQn];
    #pragma unroll
    for (int r = 0; r < RQn; r++) bqv[r] = sq[w * 480 + r * CHDIM + NHEADS + d];
    #pragma unroll
    for (int h = 0; h < NHEADS; h++) {
        float accq = 0.0f;
        #pragma unroll
        for (int r = 0; r < RQn; r++)
            accq += sq[w * 480 + r * CHDIM + h] * bqv[r];
        q[((size_t)(b * NHEADS + h) * TT + t) * DHEAD + d] = __float2bfloat16(accq * (0.125f / 6.0f));
        float acck = 0.0f, accv = 0.0f;
        #pragma unroll
        for (int r = 0; r < RKn; r++)
            acck += skv[w * 320 + r * CHDIM + h] * rot[r];
        #pragma unroll
        for (int r = 0; r < RVn; r++)
            accv += skv[w * 320 + (RKn + r) * CHDIM + h] * rot[RKn + r];
        k[((size_t)(b * NHEADS + h) * TT + t) * DHEAD + d] = __float2bfloat16(acck * 0.5f);
        vbuf[(h * 64 + d) * 4 + w] = __float2bfloat16(accv * 0.5f);
    }
    __syncthreads();
    const int t0 = tok0 % TT;
    const int b0 = tok0 / TT;
    for (int row = threadIdx.x; row < NHEADS * DHEAD; row += 256) {
        int h = row >> 6, dd = row & 63;
        *(uint2*)&vT[((size_t)(b0 * NHEADS + h) * DHEAD + dd) * TT + t0] =
            *(const uint2*)&vbuf[(h * 64 + dd) * 4];
    }
}

// ============ front: cvt -> [gbar] -> proj GEMM -> [gbar] -> qkv ============
__global__ __launch_bounds__(256, 2) void front(
    const float* __restrict__ x, const float* __restrict__ wq,
    const float* __restrict__ wk, const float* __restrict__ wo,
    __hip_bfloat16* __restrict__ xb, __hip_bfloat16* __restrict__ wqk,
    __hip_bfloat16* __restrict__ wob, float* __restrict__ abqkv,
    __hip_bfloat16* __restrict__ qb, __hip_bfloat16* __restrict__ kb,
    __hip_bfloat16* __restrict__ vT, unsigned* __restrict__ cnt)
{
    __shared__ __align__(16) char smem[49152];
    const int g = blockIdx.x;
    const int tid = threadIdx.x;

    // phase 0: fp32 -> bf16 convert (grid-stride over float4s)
    for (int i = g * 256 + tid; i < 1515520; i += GRID * 256) {
        const float* src; __hip_bfloat16* dst; int off;
        if (i < 1048576)      { src = x;  dst = xb;           off = i; }
        else if (i < 1171456) { src = wq; dst = wqk;          off = i - 1048576; }
        else if (i < 1253376) { src = wk; dst = wqk + 491520; off = i - 1171456; }
        else                  { src = wo; dst = wob;          off = i - 1253376; }
        float4 v = *(const float4*)&src[(size_t)off * 4];
        ushort4 o;
        o.x = bf16_bits(v.x); o.y = bf16_bits(v.y);
        o.z = bf16_bits(v.z); o.w = bf16_bits(v.w);
        *(ushort4*)&dst[(size_t)off * 4] = o;
    }
    gbar(&cnt[0]);

    // phase 1: projection GEMM (448 virtual blocks)
    if (g < 448)
        dev_gemm(xb, wqk, abqkv, NQK, 1024, (g / 7) * 64, (g % 7) * 128, smem);
    gbar(&cnt[1]);

    // phase 2: qkv (1024 virtual blocks)
    dev_qkv(abqkv, qb, kb, vT, g * 2 + 0, smem);
    dev_qkv(abqkv, qb, kb, vT, g * 2 + 1, smem);
}

// ---------------- r9-verbatim: gemm_bf16 (standalone, for W_o) ----------------
__global__ __launch_bounds__(256) void gemm_bf16(
    const __hip_bfloat16* __restrict__ A, const __hip_bfloat16* __restrict__ W,
    float* __restrict__ C, int M, int N, int K)
{
    __shared__ __hip_bfloat16 Asl[2][64 * 64];
    __shared__ __hip_bfloat16 Bsl[2][128 * 64];
    const int tid = threadIdx.x;
    const int w = tid >> 6, lane = tid & 63;
    const int l16 = lane & 15, quad = lane >> 4;
    const int bm = blockIdx.y * 64, bn = blockIdx.x * 128;

    int rSA[2], cSA[2];
    #pragma unroll
    for (int j = 0; j < 2; j++) {
        int L = (w * 2 + j) * 64 + lane;
        rSA[j] = L >> 3;
        cSA[j] = (L & 7) ^ (rSA[j] & 7);
    }
    int rSB[4], cSB[4];
    #pragma unroll
    for (int j = 0; j < 4; j++) {
        int L = (w * 4 + j) * 64 + lane;
        int r = L >> 3;
        cSB[j] = (L & 7) ^ (r & 7);
        int rb = bn + r;
        rSB[j] = (rb < N) ? rb : (N - 1);
    }

    f32x4 acc[4][2];
    #pragma unroll
    for (int mt = 0; mt < 4; mt++)
        #pragma unroll
        for (int nt = 0; nt < 2; nt++)
            acc[mt][nt] = (f32x4){0.f, 0.f, 0.f, 0.f};

    const int nK = K >> 6;
    #pragma unroll
    for (int j = 0; j < 2; j++)
        __builtin_amdgcn_global_load_lds(AS1(A + (size_t)(bm + rSA[j]) * K + cSA[j] * 8),
                                         AS3(&Asl[0][(w * 2 + j) * 512]), 16, 0, 0);
    #pragma unroll
    for (int j = 0; j < 4; j++)
        __builtin_amdgcn_global_load_lds(AS1(W + (size_t)rSB[j] * K + cSB[j] * 8),
                                         AS3(&Bsl[0][(w * 4 + j) * 512]), 16, 0, 0);

    for (int kk = 0; kk < nK; kk++) {
        const int cur = kk & 1;
        __syncthreads();
        if (kk + 1 < nK) {
            const int k1 = (kk + 1) * 64;
            #pragma unroll
            for (int j = 0; j < 2; j++)
                __builtin_amdgcn_global_load_lds(AS1(A + (size_t)(bm + rSA[j]) * K + k1 + cSA[j] * 8),
                                                 AS3(&Asl[cur ^ 1][(w * 2 + j) * 512]), 16, 0, 0);
            #pragma unroll
            for (int j = 0; j < 4; j++)
                __builtin_amdgcn_global_load_lds(AS1(W + (size_t)rSB[j] * K + k1 + cSB[j] * 8),
                                                 AS3(&Bsl[cur ^ 1][(w * 4 + j) * 512]), 16, 0, 0);
        }
        #pragma unroll
        for (int ks = 0; ks < 2; ks++) {
            frag16 af[4], bf[2];
            #pragma unroll
            for (int mt = 0; mt < 4; mt++) {
                int r = mt * 16 + l16;
                af[mt] = *(const frag16*)&Asl[cur][r * 64 + (((ks * 4 + quad) ^ (r & 7)) * 8)];
            }
            #pragma unroll
            for (int nt = 0; nt < 2; nt++) {
                int r = w * 32 + nt * 16 + l16;
                bf[nt] = *(const frag16*)&Bsl[cur][r * 64 + (((ks * 4 + quad) ^ (r & 7)) * 8)];
            }
            #pragma unroll
            for (int mt = 0; mt < 4; mt++)
                #pragma unroll
                for (int nt = 0; nt < 2; nt++)
                    acc[mt][nt] = __builtin_amdgcn_mfma_f32_16x16x32_bf16(af[mt], bf[nt], acc[mt][nt], 0, 0, 0);
        }
    }
    #pragma unroll
    for (int mt = 0; mt < 4; mt++) {
        #pragma unroll
        for (int reg = 0; reg < 4; reg++) {
            int row = bm + mt * 16 + quad * 4 + reg;
            #pragma unroll
            for (int nt = 0; nt < 2; nt++) {
                int col = bn + w * 32 + nt * 16 + l16;
                if (col < N) C[(size_t)row * N + col] = acc[mt][nt][reg];
            }
        }
    }
}

// ---------------- r9-verbatim flash helpers ----------------
static __device__ __forceinline__ void build_pfrag(
    const float* s0, const float* s1, frag16 Pf[4], const int hi, const int paddr)
{
    #pragma unroll
    for (int k2 = 0; k2 < 4; k2++) {
        const float* sF = (k2 >= 2) ? s1 : s0;
        const int bs = 8 * (k2 & 1);
        unsigned int u0a = pk2(sF[bs + 0], sF[bs + 1]);
        unsigned int u0b = pk2(sF[bs + 2], sF[bs + 3]);
        unsigned int u1a = pk2(sF[bs + 4], sF[bs + 5]);
        unsigned int u1b = pk2(sF[bs + 6], sF[bs + 7]);
        unsigned int r0a = (unsigned int)__builtin_amdgcn_ds_bpermute(paddr, (int)u0a);
        unsigned int r0b = (unsigned int)__builtin_amdgcn_ds_bpermute(paddr, (int)u0b);
        unsigned int r1a = (unsigned int)__builtin_amdgcn_ds_bpermute(paddr, (int)u1a);
        unsigned int r1b = (unsigned int)__builtin_amdgcn_ds_bpermute(paddr, (int)u1b);
        union { frag16 f; unsigned int u[4]; } pf;
        pf.u[0] = hi ? r1a : u0a;
        pf.u[1] = hi ? r1b : u0b;
        pf.u[2] = hi ? u1a : r0a;
        pf.u[3] = hi ? u1b : r0b;
        Pf[k2] = pf.f;
    }
}

static __device__ __forceinline__ void attn_tile(
    const __hip_bfloat16* __restrict__ Kc, const __hip_bfloat16* __restrict__ Vc,
    const frag16 qB[4], f32x16& O0, f32x16& O1, float& lpart,
    const int l31, const int hi, const int xi, const int paddr,
    const bool domask, const int kb0, const int qlane)
{
    f32x16 ST0 = {}, ST1 = {};
    #pragma unroll
    for (int kt4 = 0; kt4 < 4; kt4++) {
        int c8 = kt4 * 2 + hi;
        frag16 kf0 = *(const frag16*)&Kc[l31 * 64 + ((c8 ^ xi) * 8)];
        frag16 kf1 = *(const frag16*)&Kc[(32 + l31) * 64 + ((c8 ^ xi) * 8)];
        ST0 = __builtin_amdgcn_mfma_f32_32x32x16_bf16(kf0, qB[kt4], ST0, 0, 0, 0);
        ST1 = __builtin_amdgcn_mfma_f32_32x32x16_bf16(kf1, qB[kt4], ST1, 0, 0, 0);
    }
    float* s0 = (float*)&ST0;
    float* s1 = (float*)&ST1;
    if (domask) {
        int kbq = kb0 + 4 * hi;
        #pragma unroll
        for (int reg = 0; reg < 16; reg++) {
            int rowc = (reg & 3) + 8 * (reg >> 2);
            if (kbq + rowc > qlane)      s0[reg] = -1e30f;
            if (kbq + 32 + rowc > qlane) s1[reg] = -1e30f;
        }
    }
    #pragma unroll
    for (int reg = 0; reg < 16; reg++) {
        float p0 = __expf(s0[reg]);
        float p1 = __expf(s1[reg]);
        s0[reg] = p0; s1[reg] = p1;
        lpart += p0 + p1;
    }
    frag16 Pf[4];
    build_pfrag(s0, s1, Pf, hi, paddr);
    #pragma unroll
    for (int k2 = 0; k2 < 4; k2++) {
        int c8 = k2 * 2 + hi;
        frag16 vf0 = *(const frag16*)&Vc[l31 * 64 + ((c8 ^ xi) * 8)];
        frag16 vf1 = *(const frag16*)&Vc[(32 + l31) * 64 + ((c8 ^ xi) * 8)];
        O0 = __builtin_amdgcn_mfma_f32_32x32x16_bf16(vf0, Pf[k2], O0, 0, 0, 0);
        O1 = __builtin_amdgcn_mfma_f32_32x32x16_bf16(vf1, Pf[k2], O1, 0, 0, 0);
    }
}

// ---------------- r9-verbatim uniform split-K flash ----------------
__global__ __launch_bounds__(256, 2) void flash_mfma(
    const __hip_bfloat16* __restrict__ q, const __hip_bfloat16* __restrict__ k,
    const __hip_bfloat16* __restrict__ vT, __hip_bfloat16* __restrict__ y,
    float* __restrict__ Op, float* __restrict__ Lp)
{
    const int g = blockIdx.x;
    const int bh = g & 31;
    const int pr = g >> 5;
    const int qthalf = pr & 7;
    const int part = pr >> 3;
    const int qt_lo = qthalf, qt_hi = 15 - qthalf;
    const int nlo = 2 * qt_lo + 2;
    const int S = 17 - nlo;
    const int b = bh >> 4, h = bh & 15;
    const int tid = threadIdx.x;
    const int w = tid >> 6;
    const int lane = tid & 63;
    const int l31 = lane & 31;
    const int hi = lane >> 5;
    const int xi = l31 & 7;
    const int paddr = (lane ^ 32) << 2;

    __shared__ __align__(16) __hip_bfloat16 KsF[2][4096];
    __shared__ __align__(16) __hip_bfloat16 VsF[2][4096];

    const size_t base = (size_t)bh * TT * DHEAD;
    const __hip_bfloat16* qb = q + base;
    const __hip_bfloat16* kb = k + base;
    const __hip_bfloat16* vb = vT + base;

    const int ktd_lo = 2 * qt_lo + (w >> 1);
    const int ktd_hi = 2 * qt_hi + (w >> 1);
    const int qlane_lo = qt_lo * 128 + w * 32 + l31;
    const int qlane_hi = qt_hi * 128 + w * 32 + l31;

    const int k0off  = part ? S : 0;
    const int nsteps = part ? 17 : ((nlo > S) ? nlo : S);

    int offK[2], offV[2];
    #pragma unroll
    for (int j = 0; j < 2; j++) {
        int Lc = w * 128 + j * 64 + lane;
        int r = Lc >> 3, c8 = Lc & 7, g8 = c8 ^ (r & 7);
        offK[j] = r * 64 + g8 * 8;
        offV[j] = r * TT + g8 * 8;
    }

    frag16 qB_hi[4], qB_lo[4];
    #pragma unroll
    for (int kt4 = 0; kt4 < 4; kt4++)
        qB_hi[kt4] = *(const frag16*)&qb[(size_t)qlane_hi * DHEAD + kt4 * 16 + hi * 8];
    if (part == 0) {
        #pragma unroll
        for (int kt4 = 0; kt4 < 4; kt4++)
            qB_lo[kt4] = *(const frag16*)&qb[(size_t)qlane_lo * DHEAD + kt4 * 16 + hi * 8];
    }

    f32x16 Olo0 = {}, Olo1 = {}, Ohi0 = {}, Ohi1 = {};
    float l_lo = 0.0f, l_hi = 0.0f;

    #pragma unroll
    for (int j = 0; j < 2; j++) {
        __builtin_amdgcn_global_load_lds(AS1(kb + (size_t)k0off * 4096 + offK[j]),
                                         AS3(&KsF[0][w * 1024 + j * 512]), 16, 0, 0);
        __builtin_amdgcn_global_load_lds(AS1(vb + (size_t)k0off * 64 + offV[j]),
                                         AS3(&VsF[0][w * 1024 + j * 512]), 16, 0, 0);
    }

    for (int kt = 0; kt < nsteps; kt++) {
        const int cur = kt & 1;
        __syncthreads();
        if (kt + 1 < nsteps) {
            const int phys1 = k0off + kt + 1;
            #pragma unroll
            for (int j = 0; j < 2; j++) {
                __builtin_amdgcn_global_load_lds(AS1(kb + (size_t)phys1 * 4096 + offK[j]),
                                                 AS3(&KsF[cur ^ 1][w * 1024 + j * 512]), 16, 0, 0);
                __builtin_amdgcn_global_load_lds(AS1(vb + (size_t)phys1 * 64 + offV[j]),
                                                 AS3(&VsF[cur ^ 1][w * 1024 + j * 512]), 16, 0, 0);
            }
        }
        const __hip_bfloat16* Kc = KsF[cur];
        const __hip_bfloat16* Vc = VsF[cur];
        if (part == 0) {
            if (kt <= ktd_lo)
                attn_tile(Kc, Vc, qB_lo, Olo0, Olo1, l_lo, l31, hi, xi, paddr,
                          kt == ktd_lo, kt * 64, qlane_lo);
            if (kt < S)
                attn_tile(Kc, Vc, qB_hi, Ohi0, Ohi1, l_hi, l31, hi, xi, paddr,
                          false, 0, qlane_hi);
        } else {
            const int phys = S + kt;
            if (phys <= ktd_hi)
                attn_tile(Kc, Vc, qB_hi, Ohi0, Ohi1, l_hi, l31, hi, xi, paddr,
                          phys == ktd_hi, phys * 64, qlane_hi);
        }
    }

    if (part == 0) {
        float lother = __int_as_float(__builtin_amdgcn_ds_bpermute(paddr, __float_as_int(l_lo)));
        float inv = 1.0f / (l_lo + lother);
        float* o0 = (float*)&Olo0;
        float* o1 = (float*)&Olo1;
        __hip_bfloat16* yp = y + ((size_t)(b * TT + qlane_lo)) * DDim + h * DHEAD;
        #pragma unroll
        for (int gg = 0; gg < 4; gg++) {
            int d0 = 8 * gg + 4 * hi;
            uint2 pa, pb;
            pa.x = pk2(o0[4*gg+0] * inv, o0[4*gg+1] * inv);
            pa.y = pk2(o0[4*gg+2] * inv, o0[4*gg+3] * inv);
            pb.x = pk2(o1[4*gg+0] * inv, o1[4*gg+1] * inv);
            pb.y = pk2(o1[4*gg+2] * inv, o1[4*gg+3] * inv);
            *(uint2*)&yp[d0] = pa;
            *(uint2*)&yp[32 + d0] = pb;
        }
    }
    {
        float lother = __int_as_float(__builtin_amdgcn_ds_bpermute(paddr, __float_as_int(l_hi)));
        float ltot = l_hi + lother;
        const int slot = bh * 8 + qthalf;
        const int rloc = w * 32 + l31;
        float* Od = Op + ((size_t)part * 256 + slot) * 8192 + (size_t)rloc * 64;
        float* o0 = (float*)&Ohi0;
        float* o1 = (float*)&Ohi1;
        #pragma unroll
        for (int gg = 0; gg < 4; gg++) {
            int d0 = 8 * gg + 4 * hi;
            *(float4*)&Od[d0]      = (float4){o0[4*gg+0], o0[4*gg+1], o0[4*gg+2], o0[4*gg+3]};
            *(float4*)&Od[32 + d0] = (float4){o1[4*gg+0], o1[4*gg+1], o1[4*gg+2], o1[4*gg+3]};
        }
        if (hi == 0) Lp[part * 32768 + slot * 128 + rloc] = ltot;
    }
}

// ---------------- r9-verbatim combine ----------------
__global__ __launch_bounds__(256) void combine(
    const float* __restrict__ Op, const float* __restrict__ Lp,
    __hip_bfloat16* __restrict__ y)
{
    int idx = blockIdx.x * 256 + threadIdx.x;
    int slot = idx >> 7, row = idx & 127;
    int bh = slot >> 3, qthalf = slot & 7;
    int b = bh >> 4, h = bh & 15;
    int qrow = (15 - qthalf) * 128 + row;
    float l0 = Lp[slot * 128 + row];
    float l1 = Lp[32768 + slot * 128 + row];
    float inv = 1.0f / (l0 + l1);
    const float* p0 = Op + (size_t)(slot * 128 + row) * 64;
    const float* p1 = p0 + 2097152;
    __hip_bfloat16* yp = y + ((size_t)(b * TT + qrow)) * DDim + h * DHEAD;
    #pragma unroll
    for (int c = 0; c < 64; c += 8) {
        float4 a0 = *(const float4*)&p0[c];
        float4 a1 = *(const float4*)&p0[c + 4];
        float4 b0 = *(const float4*)&p1[c];
        float4 b1 = *(const float4*)&p1[c + 4];
        uint4 o;
        o.x = pk2((a0.x + b0.x) * inv, (a0.y + b0.y) * inv);
        o.y = pk2((a0.z + b0.z) * inv, (a0.w + b0.w) * inv);
        o.z = pk2((a1.x + b1.x) * inv, (a1.y + b1.y) * inv);
        o.w = pk2((a1.z + b1.z) * inv, (a1.w + b1.w) * inv);
        *(uint4*)&yp[c] = o;
    }
}

extern "C" void kernel_launch(void* const* d_in, const int* in_sizes, int n_in,
                              void* d_out, int out_size, void* d_ws, size_t ws_size,
                              hipStream_t stream) {
    const float* x      = (const float*)d_in[0];
    const float* W_abq  = (const float*)d_in[1];
    const float* W_abkv = (const float*)d_in[2];
    const float* W_o    = (const float*)d_in[3];
    float* out = (float*)d_out;

    char* ws = (char*)d_ws;
    unsigned* cnt = (unsigned*)ws;               ws += 256;
    __hip_bfloat16* xb   = (__hip_bfloat16*)ws;  ws += (size_t)4194304 * 2;
    __hip_bfloat16* wqk  = (__hip_bfloat16*)ws;  ws += (size_t)NQK * 1024 * 2;
    __hip_bfloat16* wo_b = (__hip_bfloat16*)ws;  ws += (size_t)1048576 * 2;
    float* abqkv = (float*)ws;                   ws += (size_t)4096 * NQK * 4;
    __hip_bfloat16* qb = (__hip_bfloat16*)ws;    ws += (size_t)4194304 * 2;
    __hip_bfloat16* kb = (__hip_bfloat16*)ws;    ws += (size_t)4194304 * 2;
    __hip_bfloat16* vT = (__hip_bfloat16*)ws;    ws += (size_t)4194304 * 2;
    __hip_bfloat16* yb = (__hip_bfloat16*)ws;    ws += (size_t)4194304 * 2;
    float* Op = (float*)ws;                      ws += (size_t)2 * 2097152 * 4;
    float* Lp = (float*)ws;                      ws += (size_t)2 * 32768 * 4;

    hipMemsetAsync(cnt, 0, 8 * sizeof(unsigned), stream);
    front<<<dim3(GRID), dim3(256), 0, stream>>>(
        x, W_abq, W_abkv, W_o, xb, wqk, wo_b, abqkv, qb, kb, vT, cnt);
    flash_mfma<<<dim3(512), dim3(256), 0, stream>>>(qb, kb, vT, yb, Op, Lp);
    combine<<<dim3(128), dim3(256), 0, stream>>>(Op, Lp, yb);
    gemm_bf16<<<dim3(8, 64), dim3(256), 0, stream>>>(yb, wo_b, out, 4096, 1024, 1024);
}